// Round 5
// baseline (480.062 us; speedup 1.0000x reference)
//
#include <hip/hip_runtime.h>
#include <stdint.h>

typedef __bf16 bf16_t;
typedef __bf16 bf16x8 __attribute__((ext_vector_type(8)));
typedef __bf16 bf16x4 __attribute__((ext_vector_type(4)));
typedef float f32x4 __attribute__((ext_vector_type(4)));

#define DEV static __device__ __forceinline__

// problem constants
#define SB 2
#define SS 2048
#define SD 2048
#define SNQ 16
#define SNKV 8
#define SH 256
#define SWIN 1024
#define KVP 4096

DEV void async_ld16(const void* g, void* lds) {
  __builtin_amdgcn_global_load_lds(
      (const __attribute__((address_space(1))) void*)g,
      (__attribute__((address_space(3))) void*)lds, 16, 0, 0);
}

// ---------------------------------------------------------------- convert x
__global__ __launch_bounds__(256) void cvt_kernel(const float* __restrict__ in,
                                                  bf16_t* __restrict__ out) {
  int i = blockIdx.x * 256 + threadIdx.x;  // over n/4 elements
  float4 v = ((const float4*)in)[i];
  bf16x4 o = {(bf16_t)v.x, (bf16_t)v.y, (bf16_t)v.z, (bf16_t)v.w};
  *(bf16x4*)(out + (size_t)i * 4) = o;
}

// ------------------------------------------- batched transpose f32 -> bf16
__global__ __launch_bounds__(256) void wtrans_kernel(const float* __restrict__ in,
                                                     bf16_t* __restrict__ out,
                                                     int R, int C) {
  __shared__ float tile[32][33];
  const int bz = blockIdx.z;
  const float* ip = in + (size_t)bz * R * C;
  bf16_t* op = out + (size_t)bz * R * C;
  const int r0 = blockIdx.y * 32, c0 = blockIdx.x * 32;
  const int tr = threadIdx.x >> 5, tc = threadIdx.x & 31;
#pragma unroll
  for (int i = 0; i < 4; ++i)
    tile[tr + i * 8][tc] = ip[(size_t)(r0 + tr + i * 8) * C + c0 + tc];
  __syncthreads();
#pragma unroll
  for (int i = 0; i < 4; ++i)
    op[(size_t)(c0 + tr + i * 8) * R + r0 + tc] = (bf16_t)tile[tc][tr + i * 8];
}

// ------------------------------------------------- V transpose bf16 -> bf16
// kvpre [B*S][4096] (V half starts at col 2048)  ->  vt [B][NKV][H][S]
__global__ __launch_bounds__(256) void vtrans_kernel(const bf16_t* __restrict__ vbase,
                                                     bf16_t* __restrict__ vt) {
  __shared__ bf16_t tile[32][33];
  const int bz = blockIdx.z;           // b*8+kv
  const int b = bz >> 3, kv = bz & 7;
  const int t0 = blockIdx.y * 32, h0 = blockIdx.x * 32;
  const int tr = threadIdx.x >> 5, tc = threadIdx.x & 31;
  const bf16_t* ip = vbase + (size_t)b * SS * KVP + kv * SH;
#pragma unroll
  for (int i = 0; i < 4; ++i)
    tile[tr + i * 8][tc] = ip[(size_t)(t0 + tr + i * 8) * KVP + h0 + tc];
  __syncthreads();
  bf16_t* op = vt + (size_t)bz * SH * SS;
#pragma unroll
  for (int i = 0; i < 4; ++i)
    op[(size_t)(h0 + tr + i * 8) * SS + t0 + tc] = tile[tc][tr + i * 8];
}

// --------------------------------------------------------- RoPE-K (vector)
// kvpre [B*S][4096] (K half = cols 0..2047) -> kb [B][NKV][S][H] with rope.
// 8 cols/thread, bf16x8 loads/stores (pair c,c+128 handled together).
__global__ __launch_bounds__(256) void rope_k_kernel(const bf16_t* __restrict__ kpre,
                                                     bf16_t* __restrict__ kb) {
  int idx = blockIdx.x * 256 + threadIdx.x;      // B*S*NKV*16
  const int i8 = (idx & 15) << 3;                // 0..120
  const int kv = (idx >> 4) & 7;
  const int row = idx >> 7;                      // 0..4095
  const int t = row & (SS - 1), b = row >> 11;
  const size_t ib = (size_t)row * KVP + kv * SH;
  bf16x8 x1 = *(const bf16x8*)(kpre + ib + i8);
  bf16x8 x2 = *(const bf16x8*)(kpre + ib + i8 + 128);
  bf16x8 r1, r2;
#pragma unroll
  for (int e = 0; e < 8; ++e) {
    float c_ = (float)(i8 + e);
    float inv = __expf(c_ * -0.07195578f);       // ln(10000)/128
    float fr = (float)t * inv;
    float cs = __cosf(fr), sn = __sinf(fr);
    float a = (float)x1[e], b2 = (float)x2[e];
    r1[e] = (bf16_t)(a * cs - b2 * sn);
    r2[e] = (bf16_t)(b2 * cs + a * sn);
  }
  const size_t ob = ((size_t)(b * SNKV + kv) * SS + t) * SH;
  *(bf16x8*)(kb + ob + i8) = r1;
  *(bf16x8*)(kb + ob + i8 + 128) = r2;
}

// ------------------------------------------------------------------- GEMM
// C[M][N] = A[M][K] * Bt[N][K]^T ; 256 x (NBW*64) tile, BK=32, 8 waves.
// 4-deep LDS ring, counted vmcnt (T4), setprio around MFMA (T5).
template <int NBW, bool OUT_BF16>
__global__ __launch_bounds__(512, 2) void gemm_bt(const bf16_t* __restrict__ A,
                                                  const bf16_t* __restrict__ Bt,
                                                  void* __restrict__ Cout,
                                                  int M, int N, int K) {
  constexpr int BN = NBW * 64;
  constexpr int MFR = (256 / (8 / NBW)) / 16;   // m-frags per wave (8 or 4)
  constexpr int ALOADS = 2;
  constexpr int BLOADS = NBW / 2;
  constexpr int LT = ALOADS + BLOADS;
  __shared__ bf16_t As[4][256 * 32];
  __shared__ bf16_t Bs[4][BN * 32];

  const int tid = threadIdx.x, lane = tid & 63, wid = tid >> 6;
  const int nbx = N / BN;
  const int nwg = (M >> 8) * nbx;
  const int cpx = nwg >> 3;
  const int lb = (blockIdx.x & 7) * cpx + (blockIdx.x >> 3);  // XCD chunking
  const int bx = lb % nbx, by = lb / nbx;
  const int row0 = by << 8;
  const int col0 = bx * BN;
  const int wr = wid / NBW, wc = wid % NBW;
  const int lr = lane & 15, hi = lane >> 4;

  const bf16_t* Arow = A + (size_t)row0 * K;
  const bf16_t* Brow = Bt + (size_t)col0 * K;

  auto stageA = [&](int t) {
    const int k0 = t << 5;
#pragma unroll
    for (int it = 0; it < ALOADS; ++it) {
      const int f = tid + (it << 9);
      async_ld16(Arow + (size_t)(f >> 2) * K + k0 + ((f & 3) << 3),
                 (char*)As[t & 3] + f * 16);
    }
  };
  auto stageB = [&](int t) {
    const int k0 = t << 5;
#pragma unroll
    for (int it = 0; it < BLOADS; ++it) {
      const int f = tid + (it << 9);
      async_ld16(Brow + (size_t)(f >> 2) * K + k0 + ((f & 3) << 3),
                 (char*)Bs[t & 3] + f * 16);
    }
  };

  f32x4 acc[MFR][4];
#pragma unroll
  for (int m = 0; m < MFR; ++m)
#pragma unroll
    for (int n = 0; n < 4; ++n) acc[m][n] = f32x4{0.f, 0.f, 0.f, 0.f};

  const int NT = K >> 5;
  stageA(0); stageB(0); stageA(1); stageB(1); stageA(2); stageB(2);
  asm volatile("s_waitcnt vmcnt(%0)" ::"i"(2 * LT) : "memory");
  __builtin_amdgcn_s_barrier();
  __builtin_amdgcn_sched_barrier(0);

  for (int t = 0; t < NT; ++t) {
    const bf16_t* Ab = &As[t & 3][(wr * (MFR * 16)) * 32];
    const bf16_t* Bb = &Bs[t & 3][(wc * 64) * 32];
    const bool pre = (t + 3 < NT);

    bf16x8 bfr[4];
#pragma unroll
    for (int nf = 0; nf < 4; ++nf)
      bfr[nf] = *(const bf16x8*)&Bb[(nf * 16 + lr) * 32 + hi * 8];

#pragma unroll
    for (int ph = 0; ph < MFR / 4; ++ph) {
      if (pre && ph == 0) stageA(t + 3);
      if (pre && ph == (MFR / 4) - 1) stageB(t + 3);
      bf16x8 af[4];
#pragma unroll
      for (int mf = 0; mf < 4; ++mf)
        af[mf] = *(const bf16x8*)&Ab[((ph * 4 + mf) * 16 + lr) * 32 + hi * 8];
      __builtin_amdgcn_s_setprio(1);
#pragma unroll
      for (int mf = 0; mf < 4; ++mf)
#pragma unroll
        for (int nf = 0; nf < 4; ++nf)
          acc[ph * 4 + mf][nf] = __builtin_amdgcn_mfma_f32_16x16x32_bf16(
              af[mf], bfr[nf], acc[ph * 4 + mf][nf], 0, 0, 0);
      __builtin_amdgcn_s_setprio(0);
    }

    if (t + 3 < NT) {
      asm volatile("s_waitcnt vmcnt(%0)" ::"i"(2 * LT) : "memory");
    } else if (t + 2 < NT) {
      asm volatile("s_waitcnt vmcnt(%0)" ::"i"(LT) : "memory");
    } else if (t + 1 < NT) {
      asm volatile("s_waitcnt vmcnt(0)" ::: "memory");
    }
    if (t + 1 < NT) {
      __builtin_amdgcn_s_barrier();
      __builtin_amdgcn_sched_barrier(0);
    }
  }

#pragma unroll
  for (int mf = 0; mf < MFR; ++mf) {
    const int r = row0 + wr * (MFR * 16) + mf * 16 + hi * 4;
#pragma unroll
    for (int nf = 0; nf < 4; ++nf) {
      const int c = col0 + wc * 64 + nf * 16 + lr;
#pragma unroll
      for (int j = 0; j < 4; ++j) {
        if (OUT_BF16)
          ((bf16_t*)Cout)[(size_t)(r + j) * N + c] = (bf16_t)acc[mf][nf][j];
        else
          ((float*)Cout)[(size_t)(r + j) * N + c] = acc[mf][nf][j];
      }
    }
  }
}

// -------------------------------------------------------------- attention
// Per block: (b, head, 128 q rows), 8 waves x 16 q rows each.
// RoPE on Q fused into the Q register load (each Q row read exactly once).
// Fixed-base softmax (softcap bounds logits to +-50).
// KVB=32: LDS = Ks 2x16K + Vs 2x16K + Ps 10K = 74 KB -> 2 blocks/CU.
#define QB 128
#define KVB 32
#define PP 40    // Ps pitch 80B (16B-aligned rows, ~balanced banks)

__global__ __launch_bounds__(512, 4) void attn_kernel(
    const bf16_t* __restrict__ Q,   // [B*S][NQ*H] (RAW projection output)
    const bf16_t* __restrict__ Kt,  // [B][NKV][S][H] (roped)
    const bf16_t* __restrict__ Vt,  // [B][NKV][H][S]
    bf16_t* __restrict__ AV) {      // [B*S][NQ*H]
  __shared__ bf16_t Ks[2][KVB * SH];   // 2 x 16 KB, row pitch 512B
  __shared__ bf16_t Vs[2][SH * KVB];   // 2 x 16 KB, row pitch 64B
  __shared__ bf16_t Ps[QB * PP];       // 10 KB

  const int tid = threadIdx.x, lane = tid & 63, wid = tid >> 6;
  const int lb = (blockIdx.x & 7) * 64 + (blockIdx.x >> 3);
  const int qt = lb & 15;
  const int head = (((lb >> 5) & 7) << 1) | ((lb >> 4) & 1);
  const int b = lb >> 8;
  const int kvh = head >> 1;
  const int t0 = qt << 7;
  const int trw = t0 + wid * 16;       // this wave's first q row
  const int lr = lane & 15, hi = lane >> 4;
  const int lk = hi << 3;
  const int lq = hi;

  // Q load + fused RoPE + 1/16 scale (pair (c, c+128) = qf[ks], qf[ks+4])
  bf16x8 qf[8];
  {
    const bf16_t* qp = Q + ((size_t)(b * SS + trw + lr)) * (SNQ * SH) + head * SH + lk;
#pragma unroll
    for (int ks = 0; ks < 8; ++ks) qf[ks] = *(const bf16x8*)(qp + ks * 32);
    const float tpos = (float)(trw + lr);
#pragma unroll
    for (int ks = 0; ks < 4; ++ks) {
      bf16x8 a = qf[ks], b2 = qf[ks + 4];
      bf16x8 ra, rb;
#pragma unroll
      for (int e = 0; e < 8; ++e) {
        float c_ = (float)(ks * 32 + lk + e);
        float inv = __expf(c_ * -0.07195578f);
        float fr = tpos * inv;
        float cs = __cosf(fr), sn = __sinf(fr);
        float x1 = (float)a[e], x2 = (float)b2[e];
        ra[e] = (bf16_t)((x1 * cs - x2 * sn) * 0.0625f);
        rb[e] = (bf16_t)((x2 * cs + x1 * sn) * 0.0625f);
      }
      qf[ks] = ra; qf[ks + 4] = rb;
    }
  }

  f32x4 o[16];
#pragma unroll
  for (int i = 0; i < 16; ++i) o[i] = f32x4{0.f, 0.f, 0.f, 0.f};
  float lsum[4] = {0.f, 0.f, 0.f, 0.f};

  const bf16_t* Kb = Kt + (size_t)(b * SNKV + kvh) * SS * SH;
  const bf16_t* Vb = Vt + (size_t)(b * SNKV + kvh) * SH * SS;

  const int sv0 = (t0 >= SWIN) ? ((t0 - SWIN + 1) >> 5) : 0;
  const int sv1 = (t0 >> 5) + 3;

  // DMA-stage K (32x256) + V^T (256x32) into buf d; both-sides XOR swizzle.
  auto stage = [&](int s0, int d) {
#pragma unroll
    for (int it = 0; it < 2; ++it) {
      const int f = tid + (it << 9);           // 0..1023
      {
        const int r = f >> 5, pc = f & 31;
        const int sc = pc ^ (r & 7);
        async_ld16(Kb + (size_t)(s0 + r) * SH + sc * 8, (char*)Ks[d] + f * 16);
      }
      {
        const int r = f >> 2, pc = f & 3;
        const int sc = pc ^ (r & 3);
        async_ld16(Vb + (size_t)r * SS + s0 + sc * 8, (char*)Vs[d] + f * 16);
      }
    }
  };

  stage(sv0 << 5, 0);
  __syncthreads();

  int cur = 0;
  for (int sv = sv0; sv <= sv1; ++sv, cur ^= 1) {
    if (sv < sv1) stage((sv + 1) << 5, cur ^ 1);

    const int s0 = sv << 5;
    const bool skip = (s0 > trw + 15) || (s0 + 31 < trw - (SWIN - 1));
    if (!skip) {
      const bf16_t* Kc = Ks[cur];
      const bf16_t* Vc = Vs[cur];
      // S = Q K^T (2 col-frags of 16)
      f32x4 sacc[2];
#pragma unroll
      for (int nt = 0; nt < 2; ++nt) sacc[nt] = f32x4{0.f, 0.f, 0.f, 0.f};
      __builtin_amdgcn_s_setprio(1);
#pragma unroll
      for (int ks = 0; ks < 8; ++ks) {
#pragma unroll
        for (int nt = 0; nt < 2; ++nt) {
          const int R = nt * 16 + lr;
          bf16x8 kf = *(const bf16x8*)((const char*)Kc + R * 512 +
                                       (((ks * 4 + hi) ^ (R & 7)) << 4));
          sacc[nt] = __builtin_amdgcn_mfma_f32_16x16x32_bf16(qf[ks], kf, sacc[nt], 0, 0, 0);
        }
      }
      __builtin_amdgcn_s_setprio(0);

      // softcap + exp (fixed base), write P
      const bool full = (s0 + 31 <= trw) && (s0 >= trw + 15 - (SWIN - 1));
      if (full) {
#pragma unroll
        for (int nt = 0; nt < 2; ++nt) {
#pragma unroll
          for (int j = 0; j < 4; ++j) {
            float u = sacc[nt][j] * 0.04f;
            float th = 50.f - 100.f * __builtin_amdgcn_rcpf(__expf(u) + 1.f);
            float p = __expf(th);
            lsum[j] += p;
            Ps[(wid * 16 + lq * 4 + j) * PP + nt * 16 + lr] = (bf16_t)p;
          }
        }
      } else {
#pragma unroll
        for (int nt = 0; nt < 2; ++nt) {
          const int s_ = s0 + nt * 16 + lr;
#pragma unroll
          for (int j = 0; j < 4; ++j) {
            const int t_ = trw + lq * 4 + j;
            float u = sacc[nt][j] * 0.04f;
            float th = 50.f - 100.f * __builtin_amdgcn_rcpf(__expf(u) + 1.f);
            const bool valid = (s_ <= t_) && (t_ - s_ < SWIN);
            float p = valid ? __expf(th) : 0.f;
            lsum[j] += p;
            Ps[(wid * 16 + lq * 4 + j) * PP + nt * 16 + lr] = (bf16_t)p;
          }
        }
      }

      // O += P V   (P rows wave-local; K-dim = 32 -> single pf frag)
      __builtin_amdgcn_s_setprio(1);
      bf16x8 pf = *(const bf16x8*)&Ps[(wid * 16 + lr) * PP + lk];
#pragma unroll
      for (int nt = 0; nt < 16; ++nt) {
        const int R = nt * 16 + lr;
        bf16x8 vf = *(const bf16x8*)((const char*)Vc + R * 64 +
                                     ((hi ^ (R & 3)) << 4));
        o[nt] = __builtin_amdgcn_mfma_f32_16x16x32_bf16(pf, vf, o[nt], 0, 0, 0);
      }
      __builtin_amdgcn_s_setprio(0);
    }

    __syncthreads();
  }

#pragma unroll
  for (int j = 0; j < 4; ++j) {
    float l = lsum[j];
    l += __shfl_xor(l, 1);
    l += __shfl_xor(l, 2);
    l += __shfl_xor(l, 4);
    l += __shfl_xor(l, 8);
    const float inv = 1.f / l;
    const int t_ = trw + lq * 4 + j;
    bf16_t* op = AV + ((size_t)(b * SS + t_)) * (SNQ * SH) + head * SH;
#pragma unroll
    for (int nt = 0; nt < 16; ++nt) op[nt * 16 + lr] = (bf16_t)(o[nt][j] * inv);
  }
}

// ------------------------------------------------------------------- host
extern "C" void kernel_launch(void* const* d_in, const int* in_sizes, int n_in,
                              void* d_out, int out_size, void* d_ws, size_t ws_size,
                              hipStream_t stream) {
  const float* x = (const float*)d_in[0];
  const float* Wq = (const float*)d_in[1];
  const float* Wk = (const float*)d_in[2];
  const float* Wv = (const float*)d_in[3];
  const float* Wo = (const float*)d_in[4];
  float* out = (float*)d_out;

  char* ws = (char*)d_ws;
  size_t off = 0;
  auto alloc = [&](size_t elems) {
    bf16_t* p = (bf16_t*)(ws + off);
    off += ((elems * 2 + 255) & ~(size_t)255);
    return p;
  };
  const size_t MS = (size_t)SB * SS;        // 4096 rows
  bf16_t* xb    = alloc(MS * SD);                 // [4096][2048]
  bf16_t* wqT   = alloc((size_t)SNQ * SH * SD);   // [4096][2048]
  bf16_t* wkvT  = alloc((size_t)2 * SNKV * SH * SD); // K rows then V rows
  bf16_t* woT   = alloc((size_t)SD * SNQ * SH);   // [2048][4096]
  bf16_t* qb    = alloc(MS * SNQ * SH);           // [4096][4096]
  bf16_t* kvpre = alloc(MS * 2 * SNKV * SH);      // [4096][4096] K | V cols
  bf16_t* kb    = alloc(MS * SNKV * SH);          // [B][NKV][S][H]
  bf16_t* vt    = alloc(MS * SNKV * SH);          // [B][NKV][H][S]
  bf16_t* av    = alloc(MS * SNQ * SH);           // [4096][4096]
  (void)ws_size;  // ~218 MB

  cvt_kernel<<<(MS * SD / 4) / 256, 256, 0, stream>>>(x, xb);
  wtrans_kernel<<<dim3(8, 64, 16), 256, 0, stream>>>(Wq, wqT, SD, SH);
  wtrans_kernel<<<dim3(8, 64, 8), 256, 0, stream>>>(Wk, wkvT, SD, SH);
  wtrans_kernel<<<dim3(8, 64, 8), 256, 0, stream>>>(Wv, wkvT + (size_t)SNKV * SH * SD, SD, SH);
  wtrans_kernel<<<dim3(64, 128, 1), 256, 0, stream>>>(Wo, woT, SNQ * SH, SD);

  gemm_bt<4, true><<<256, 512, 0, stream>>>(xb, wqT, qb, 4096, 4096, 2048);
  gemm_bt<4, true><<<256, 512, 0, stream>>>(xb, wkvT, kvpre, 4096, 4096, 2048);

  rope_k_kernel<<<(MS * SNKV * 16) / 256, 256, 0, stream>>>(kvpre, kb);
  vtrans_kernel<<<dim3(8, 64, 16), 256, 0, stream>>>(kvpre + 2048, vt);

  attn_kernel<<<512, 512, 0, stream>>>(qb, kb, vt, av);

  gemm_bt<2, false><<<256, 512, 0, stream>>>(av, woT, out, 4096, 2048, 4096);
}

// Round 6
// 464.743 us; speedup vs baseline: 1.0330x; 1.0330x over previous
//
#include <hip/hip_runtime.h>
#include <stdint.h>

typedef __bf16 bf16_t;
typedef __bf16 bf16x8 __attribute__((ext_vector_type(8)));
typedef __bf16 bf16x4 __attribute__((ext_vector_type(4)));
typedef float f32x4 __attribute__((ext_vector_type(4)));

#define DEV static __device__ __forceinline__

// problem constants
#define SB 2
#define SS 2048
#define SD 2048
#define SNQ 16
#define SNKV 8
#define SH 256
#define SWIN 1024
#define KVP 4096

DEV void async_ld16(const void* g, void* lds) {
  __builtin_amdgcn_global_load_lds(
      (const __attribute__((address_space(1))) void*)g,
      (__attribute__((address_space(3))) void*)lds, 16, 0, 0);
}

// ---------------------------------------------------------------- convert x
__global__ __launch_bounds__(256) void cvt_kernel(const float* __restrict__ in,
                                                  bf16_t* __restrict__ out) {
  int i = blockIdx.x * 256 + threadIdx.x;  // over n/4 elements
  float4 v = ((const float4*)in)[i];
  bf16x4 o = {(bf16_t)v.x, (bf16_t)v.y, (bf16_t)v.z, (bf16_t)v.w};
  *(bf16x4*)(out + (size_t)i * 4) = o;
}

// ------------------------------------------- batched transpose f32 -> bf16
__global__ __launch_bounds__(256) void wtrans_kernel(const float* __restrict__ in,
                                                     bf16_t* __restrict__ out,
                                                     int R, int C) {
  __shared__ float tile[32][33];
  const int bz = blockIdx.z;
  const float* ip = in + (size_t)bz * R * C;
  bf16_t* op = out + (size_t)bz * R * C;
  const int r0 = blockIdx.y * 32, c0 = blockIdx.x * 32;
  const int tr = threadIdx.x >> 5, tc = threadIdx.x & 31;
#pragma unroll
  for (int i = 0; i < 4; ++i)
    tile[tr + i * 8][tc] = ip[(size_t)(r0 + tr + i * 8) * C + c0 + tc];
  __syncthreads();
#pragma unroll
  for (int i = 0; i < 4; ++i)
    op[(size_t)(c0 + tr + i * 8) * R + r0 + tc] = (bf16_t)tile[tc][tr + i * 8];
}

// ------------------------------------------------- V transpose bf16 -> bf16
// kvpre [B*S][4096] (V half starts at col 2048)  ->  vt [B][NKV][H][S]
__global__ __launch_bounds__(256) void vtrans_kernel(const bf16_t* __restrict__ vbase,
                                                     bf16_t* __restrict__ vt) {
  __shared__ bf16_t tile[32][33];
  const int bz = blockIdx.z;           // b*8+kv
  const int b = bz >> 3, kv = bz & 7;
  const int t0 = blockIdx.y * 32, h0 = blockIdx.x * 32;
  const int tr = threadIdx.x >> 5, tc = threadIdx.x & 31;
  const bf16_t* ip = vbase + (size_t)b * SS * KVP + kv * SH;
#pragma unroll
  for (int i = 0; i < 4; ++i)
    tile[tr + i * 8][tc] = ip[(size_t)(t0 + tr + i * 8) * KVP + h0 + tc];
  __syncthreads();
  bf16_t* op = vt + (size_t)bz * SH * SS;
#pragma unroll
  for (int i = 0; i < 4; ++i)
    op[(size_t)(h0 + tr + i * 8) * SS + t0 + tc] = tile[tc][tr + i * 8];
}

// --------------------------------------------------------- RoPE-K (vector)
__global__ __launch_bounds__(256) void rope_k_kernel(const bf16_t* __restrict__ kpre,
                                                     bf16_t* __restrict__ kb) {
  int idx = blockIdx.x * 256 + threadIdx.x;      // B*S*NKV*16
  const int i8 = (idx & 15) << 3;                // 0..120
  const int kv = (idx >> 4) & 7;
  const int row = idx >> 7;                      // 0..4095
  const int t = row & (SS - 1), b = row >> 11;
  const size_t ib = (size_t)row * KVP + kv * SH;
  bf16x8 x1 = *(const bf16x8*)(kpre + ib + i8);
  bf16x8 x2 = *(const bf16x8*)(kpre + ib + i8 + 128);
  bf16x8 r1, r2;
#pragma unroll
  for (int e = 0; e < 8; ++e) {
    float c_ = (float)(i8 + e);
    float inv = __expf(c_ * -0.07195578f);       // ln(10000)/128
    float fr = (float)t * inv;
    float cs = __cosf(fr), sn = __sinf(fr);
    float a = (float)x1[e], b2 = (float)x2[e];
    r1[e] = (bf16_t)(a * cs - b2 * sn);
    r2[e] = (bf16_t)(b2 * cs + a * sn);
  }
  const size_t ob = ((size_t)(b * SNKV + kv) * SS + t) * SH;
  *(bf16x8*)(kb + ob + i8) = r1;
  *(bf16x8*)(kb + ob + i8 + 128) = r2;
}

// ------------------------------------------------------------------- GEMM
// C[M][N] = A[M][K] * Bt[N][K]^T ; 256 x (NBW*64) tile, BK=32, 8 waves.
// 4-deep LDS ring, counted vmcnt (T4), setprio around MFMA (T5).
template <int NBW, bool OUT_BF16>
__global__ __launch_bounds__(512, 2) void gemm_bt(const bf16_t* __restrict__ A,
                                                  const bf16_t* __restrict__ Bt,
                                                  void* __restrict__ Cout,
                                                  int M, int N, int K) {
  constexpr int BN = NBW * 64;
  constexpr int MFR = (256 / (8 / NBW)) / 16;   // m-frags per wave (8 or 4)
  constexpr int ALOADS = 2;
  constexpr int BLOADS = NBW / 2;
  constexpr int LT = ALOADS + BLOADS;
  __shared__ bf16_t As[4][256 * 32];
  __shared__ bf16_t Bs[4][BN * 32];

  const int tid = threadIdx.x, lane = tid & 63, wid = tid >> 6;
  const int nbx = N / BN;
  const int nwg = (M >> 8) * nbx;
  const int cpx = nwg >> 3;
  const int lb = (blockIdx.x & 7) * cpx + (blockIdx.x >> 3);  // XCD chunking
  const int bx = lb % nbx, by = lb / nbx;
  const int row0 = by << 8;
  const int col0 = bx * BN;
  const int wr = wid / NBW, wc = wid % NBW;
  const int lr = lane & 15, hi = lane >> 4;

  const bf16_t* Arow = A + (size_t)row0 * K;
  const bf16_t* Brow = Bt + (size_t)col0 * K;

  auto stageA = [&](int t) {
    const int k0 = t << 5;
#pragma unroll
    for (int it = 0; it < ALOADS; ++it) {
      const int f = tid + (it << 9);
      async_ld16(Arow + (size_t)(f >> 2) * K + k0 + ((f & 3) << 3),
                 (char*)As[t & 3] + f * 16);
    }
  };
  auto stageB = [&](int t) {
    const int k0 = t << 5;
#pragma unroll
    for (int it = 0; it < BLOADS; ++it) {
      const int f = tid + (it << 9);
      async_ld16(Brow + (size_t)(f >> 2) * K + k0 + ((f & 3) << 3),
                 (char*)Bs[t & 3] + f * 16);
    }
  };

  f32x4 acc[MFR][4];
#pragma unroll
  for (int m = 0; m < MFR; ++m)
#pragma unroll
    for (int n = 0; n < 4; ++n) acc[m][n] = f32x4{0.f, 0.f, 0.f, 0.f};

  const int NT = K >> 5;
  stageA(0); stageB(0); stageA(1); stageB(1); stageA(2); stageB(2);
  asm volatile("s_waitcnt vmcnt(%0)" ::"i"(2 * LT) : "memory");
  __builtin_amdgcn_s_barrier();
  __builtin_amdgcn_sched_barrier(0);

  for (int t = 0; t < NT; ++t) {
    const bf16_t* Ab = &As[t & 3][(wr * (MFR * 16)) * 32];
    const bf16_t* Bb = &Bs[t & 3][(wc * 64) * 32];
    const bool pre = (t + 3 < NT);

    bf16x8 bfr[4];
#pragma unroll
    for (int nf = 0; nf < 4; ++nf)
      bfr[nf] = *(const bf16x8*)&Bb[(nf * 16 + lr) * 32 + hi * 8];

#pragma unroll
    for (int ph = 0; ph < MFR / 4; ++ph) {
      if (pre && ph == 0) stageA(t + 3);
      if (pre && ph == (MFR / 4) - 1) stageB(t + 3);
      bf16x8 af[4];
#pragma unroll
      for (int mf = 0; mf < 4; ++mf)
        af[mf] = *(const bf16x8*)&Ab[((ph * 4 + mf) * 16 + lr) * 32 + hi * 8];
      __builtin_amdgcn_s_setprio(1);
#pragma unroll
      for (int mf = 0; mf < 4; ++mf)
#pragma unroll
        for (int nf = 0; nf < 4; ++nf)
          acc[ph * 4 + mf][nf] = __builtin_amdgcn_mfma_f32_16x16x32_bf16(
              af[mf], bfr[nf], acc[ph * 4 + mf][nf], 0, 0, 0);
      __builtin_amdgcn_s_setprio(0);
    }

    if (t + 3 < NT) {
      asm volatile("s_waitcnt vmcnt(%0)" ::"i"(2 * LT) : "memory");
    } else if (t + 2 < NT) {
      asm volatile("s_waitcnt vmcnt(%0)" ::"i"(LT) : "memory");
    } else if (t + 1 < NT) {
      asm volatile("s_waitcnt vmcnt(0)" ::: "memory");
    }
    if (t + 1 < NT) {
      __builtin_amdgcn_s_barrier();
      __builtin_amdgcn_sched_barrier(0);
    }
  }

#pragma unroll
  for (int mf = 0; mf < MFR; ++mf) {
    const int r = row0 + wr * (MFR * 16) + mf * 16 + hi * 4;
#pragma unroll
    for (int nf = 0; nf < 4; ++nf) {
      const int c = col0 + wc * 64 + nf * 16 + lr;
#pragma unroll
      for (int j = 0; j < 4; ++j) {
        if (OUT_BF16)
          ((bf16_t*)Cout)[(size_t)(r + j) * N + c] = (bf16_t)acc[mf][nf][j];
        else
          ((float*)Cout)[(size_t)(r + j) * N + c] = acc[mf][nf][j];
      }
    }
  }
}

// -------------------------------------------------------------- attention
// Per block: (b, head, 128 q rows), 8 waves x 16 q rows each.
// RoPE on Q fused into the Q register load. Fixed-base softmax.
// KVB=32: LDS = Ks 2x16K + Vs 2x16K + Ps 10K = 74 KB -> 2 blocks/CU
// (VGPR must stay <=128; launch_bounds(512,2) gave 88 in R3/R4).
// Swizzles (both-sides XOR involutions, verified 2-way max):
//   K (512B pitch): chunk ^= (row & 7)
//   V (64B pitch):  chunk ^= ((row >> 1) & 3)   [parity rows alternate halves]
#define QB 128
#define KVB 32
#define PP 40    // Ps pitch 80B (16B-aligned rows)

__global__ __launch_bounds__(512, 2) void attn_kernel(
    const bf16_t* __restrict__ Q,   // [B*S][NQ*H] (RAW projection output)
    const bf16_t* __restrict__ Kt,  // [B][NKV][S][H] (roped)
    const bf16_t* __restrict__ Vt,  // [B][NKV][H][S]
    bf16_t* __restrict__ AV) {      // [B*S][NQ*H]
  __shared__ bf16_t Ks[2][KVB * SH];   // 2 x 16 KB, row pitch 512B
  __shared__ bf16_t Vs[2][SH * KVB];   // 2 x 16 KB, row pitch 64B
  __shared__ bf16_t Ps[QB * PP];       // 10 KB

  const int tid = threadIdx.x, lane = tid & 63, wid = tid >> 6;
  const int lb = (blockIdx.x & 7) * 64 + (blockIdx.x >> 3);
  const int qt = lb & 15;
  const int head = (((lb >> 5) & 7) << 1) | ((lb >> 4) & 1);
  const int b = lb >> 8;
  const int kvh = head >> 1;
  const int t0 = qt << 7;
  const int trw = t0 + wid * 16;       // this wave's first q row
  const int lr = lane & 15, hi = lane >> 4;
  const int lk = hi << 3;
  const int lq = hi;

  // Q load + fused RoPE + 1/16 scale (pair (c, c+128) = qf[ks], qf[ks+4])
  bf16x8 qf[8];
  {
    const bf16_t* qp = Q + ((size_t)(b * SS + trw + lr)) * (SNQ * SH) + head * SH + lk;
#pragma unroll
    for (int ks = 0; ks < 8; ++ks) qf[ks] = *(const bf16x8*)(qp + ks * 32);
    const float tpos = (float)(trw + lr);
#pragma unroll
    for (int ks = 0; ks < 4; ++ks) {
      bf16x8 a = qf[ks], b2 = qf[ks + 4];
      bf16x8 ra, rb;
#pragma unroll
      for (int e = 0; e < 8; ++e) {
        float c_ = (float)(ks * 32 + lk + e);
        float inv = __expf(c_ * -0.07195578f);
        float fr = tpos * inv;
        float cs = __cosf(fr), sn = __sinf(fr);
        float x1 = (float)a[e], x2 = (float)b2[e];
        ra[e] = (bf16_t)((x1 * cs - x2 * sn) * 0.0625f);
        rb[e] = (bf16_t)((x2 * cs + x1 * sn) * 0.0625f);
      }
      qf[ks] = ra; qf[ks + 4] = rb;
    }
  }

  f32x4 o[16];
#pragma unroll
  for (int i = 0; i < 16; ++i) o[i] = f32x4{0.f, 0.f, 0.f, 0.f};
  float lsum[4] = {0.f, 0.f, 0.f, 0.f};

  const bf16_t* Kb = Kt + (size_t)(b * SNKV + kvh) * SS * SH;
  const bf16_t* Vb = Vt + (size_t)(b * SNKV + kvh) * SH * SS;

  const int sv0 = (t0 >= SWIN) ? ((t0 - SWIN + 1) >> 5) : 0;
  const int sv1 = (t0 >> 5) + 3;

  auto stage = [&](int s0, int d) {
#pragma unroll
    for (int it = 0; it < 2; ++it) {
      const int f = tid + (it << 9);           // 0..1023
      {
        const int r = f >> 5, pc = f & 31;
        const int sc = pc ^ (r & 7);
        async_ld16(Kb + (size_t)(s0 + r) * SH + sc * 8, (char*)Ks[d] + f * 16);
      }
      {
        const int r = f >> 2, pc = f & 3;
        const int sc = pc ^ ((r >> 1) & 3);
        async_ld16(Vb + (size_t)r * SS + s0 + sc * 8, (char*)Vs[d] + f * 16);
      }
    }
  };

  stage(sv0 << 5, 0);
  __syncthreads();

  int cur = 0;
  for (int sv = sv0; sv <= sv1; ++sv, cur ^= 1) {
    if (sv < sv1) stage((sv + 1) << 5, cur ^ 1);

    const int s0 = sv << 5;
    const bool skip = (s0 > trw + 15) || (s0 + 31 < trw - (SWIN - 1));
    if (!skip) {
      const bf16_t* Kc = Ks[cur];
      const bf16_t* Vc = Vs[cur];
      // S = Q K^T (2 col-frags of 16)
      f32x4 sacc[2];
#pragma unroll
      for (int nt = 0; nt < 2; ++nt) sacc[nt] = f32x4{0.f, 0.f, 0.f, 0.f};
      __builtin_amdgcn_s_setprio(1);
#pragma unroll
      for (int ks = 0; ks < 8; ++ks) {
#pragma unroll
        for (int nt = 0; nt < 2; ++nt) {
          const int R = nt * 16 + lr;
          bf16x8 kf = *(const bf16x8*)((const char*)Kc + R * 512 +
                                       (((ks * 4 + hi) ^ (R & 7)) << 4));
          sacc[nt] = __builtin_amdgcn_mfma_f32_16x16x32_bf16(qf[ks], kf, sacc[nt], 0, 0, 0);
        }
      }
      __builtin_amdgcn_s_setprio(0);

      // softcap + exp (fixed base), write P
      const bool full = (s0 + 31 <= trw) && (s0 >= trw + 15 - (SWIN - 1));
      if (full) {
#pragma unroll
        for (int nt = 0; nt < 2; ++nt) {
#pragma unroll
          for (int j = 0; j < 4; ++j) {
            float u = sacc[nt][j] * 0.04f;
            float th = 50.f - 100.f * __builtin_amdgcn_rcpf(__expf(u) + 1.f);
            float p = __expf(th);
            lsum[j] += p;
            Ps[(wid * 16 + lq * 4 + j) * PP + nt * 16 + lr] = (bf16_t)p;
          }
        }
      } else {
#pragma unroll
        for (int nt = 0; nt < 2; ++nt) {
          const int s_ = s0 + nt * 16 + lr;
#pragma unroll
          for (int j = 0; j < 4; ++j) {
            const int t_ = trw + lq * 4 + j;
            float u = sacc[nt][j] * 0.04f;
            float th = 50.f - 100.f * __builtin_amdgcn_rcpf(__expf(u) + 1.f);
            const bool valid = (s_ <= t_) && (t_ - s_ < SWIN);
            float p = valid ? __expf(th) : 0.f;
            lsum[j] += p;
            Ps[(wid * 16 + lq * 4 + j) * PP + nt * 16 + lr] = (bf16_t)p;
          }
        }
      }

      // O += P V   (P rows wave-local; K-dim = 32 -> single pf frag)
      __builtin_amdgcn_s_setprio(1);
      bf16x8 pf = *(const bf16x8*)&Ps[(wid * 16 + lr) * PP + lk];
#pragma unroll
      for (int nt = 0; nt < 16; ++nt) {
        const int R = nt * 16 + lr;
        bf16x8 vf = *(const bf16x8*)((const char*)Vc + R * 64 +
                                     ((hi ^ ((R >> 1) & 3)) << 4));
        o[nt] = __builtin_amdgcn_mfma_f32_16x16x32_bf16(pf, vf, o[nt], 0, 0, 0);
      }
      __builtin_amdgcn_s_setprio(0);
    }

    __syncthreads();
  }

#pragma unroll
  for (int j = 0; j < 4; ++j) {
    float l = lsum[j];
    l += __shfl_xor(l, 1);
    l += __shfl_xor(l, 2);
    l += __shfl_xor(l, 4);
    l += __shfl_xor(l, 8);
    const float inv = 1.f / l;
    const int t_ = trw + lq * 4 + j;
    bf16_t* op = AV + ((size_t)(b * SS + t_)) * (SNQ * SH) + head * SH;
#pragma unroll
    for (int nt = 0; nt < 16; ++nt) op[nt * 16 + lr] = (bf16_t)(o[nt][j] * inv);
  }
}

// ------------------------------------------------------------------- host
extern "C" void kernel_launch(void* const* d_in, const int* in_sizes, int n_in,
                              void* d_out, int out_size, void* d_ws, size_t ws_size,
                              hipStream_t stream) {
  const float* x = (const float*)d_in[0];
  const float* Wq = (const float*)d_in[1];
  const float* Wk = (const float*)d_in[2];
  const float* Wv = (const float*)d_in[3];
  const float* Wo = (const float*)d_in[4];
  float* out = (float*)d_out;

  char* ws = (char*)d_ws;
  size_t off = 0;
  auto alloc = [&](size_t elems) {
    bf16_t* p = (bf16_t*)(ws + off);
    off += ((elems * 2 + 255) & ~(size_t)255);
    return p;
  };
  const size_t MS = (size_t)SB * SS;        // 4096 rows
  bf16_t* xb    = alloc(MS * SD);                 // [4096][2048]
  bf16_t* wqT   = alloc((size_t)SNQ * SH * SD);   // [4096][2048]
  bf16_t* wkvT  = alloc((size_t)2 * SNKV * SH * SD); // K rows then V rows
  bf16_t* woT   = alloc((size_t)SD * SNQ * SH);   // [2048][4096]
  bf16_t* qb    = alloc(MS * SNQ * SH);           // [4096][4096]
  bf16_t* kvpre = alloc(MS * 2 * SNKV * SH);      // [4096][4096] K | V cols
  bf16_t* kb    = alloc(MS * SNKV * SH);          // [B][NKV][S][H]
  bf16_t* vt    = alloc(MS * SNKV * SH);          // [B][NKV][H][S]
  bf16_t* av    = alloc(MS * SNQ * SH);           // [4096][4096]
  (void)ws_size;  // ~218 MB

  cvt_kernel<<<(MS * SD / 4) / 256, 256, 0, stream>>>(x, xb);
  wtrans_kernel<<<dim3(8, 64, 16), 256, 0, stream>>>(Wq, wqT, SD, SH);
  wtrans_kernel<<<dim3(8, 64, 8), 256, 0, stream>>>(Wk, wkvT, SD, SH);
  wtrans_kernel<<<dim3(8, 64, 8), 256, 0, stream>>>(Wv, wkvT + (size_t)SNKV * SH * SD, SD, SH);
  wtrans_kernel<<<dim3(64, 128, 1), 256, 0, stream>>>(Wo, woT, SNQ * SH, SD);

  gemm_bt<4, true><<<256, 512, 0, stream>>>(xb, wqT, qb, 4096, 4096, 2048);
  gemm_bt<4, true><<<256, 512, 0, stream>>>(xb, wkvT, kvpre, 4096, 4096, 2048);

  rope_k_kernel<<<(MS * SNKV * 16) / 256, 256, 0, stream>>>(kvpre, kb);
  vtrans_kernel<<<dim3(8, 64, 16), 256, 0, stream>>>(kvpre + 2048, vt);

  attn_kernel<<<512, 512, 0, stream>>>(qb, kb, vt, av);

  gemm_bt<2, false><<<256, 512, 0, stream>>>(av, woT, out, 4096, 2048, 4096);
}

// Round 7
// 445.347 us; speedup vs baseline: 1.0779x; 1.0436x over previous
//
#include <hip/hip_runtime.h>
#include <stdint.h>

typedef __bf16 bf16_t;
typedef __bf16 bf16x8 __attribute__((ext_vector_type(8)));
typedef __bf16 bf16x4 __attribute__((ext_vector_type(4)));
typedef float f32x4 __attribute__((ext_vector_type(4)));

#define DEV static __device__ __forceinline__

// problem constants
#define SB 2
#define SS 2048
#define SD 2048
#define SNQ 16
#define SNKV 8
#define SH 256
#define SWIN 1024
#define KVP 4096

DEV void async_ld16(const void* g, void* lds) {
  __builtin_amdgcn_global_load_lds(
      (const __attribute__((address_space(1))) void*)g,
      (__attribute__((address_space(3))) void*)lds, 16, 0, 0);
}

// ---------------------------------------------------------------- convert x
__global__ __launch_bounds__(256) void cvt_kernel(const float* __restrict__ in,
                                                  bf16_t* __restrict__ out) {
  int i = blockIdx.x * 256 + threadIdx.x;  // over n/4 elements
  float4 v = ((const float4*)in)[i];
  bf16x4 o = {(bf16_t)v.x, (bf16_t)v.y, (bf16_t)v.z, (bf16_t)v.w};
  *(bf16x4*)(out + (size_t)i * 4) = o;
}

// ------------------------------------------- batched transpose f32 -> bf16
__global__ __launch_bounds__(256) void wtrans_kernel(const float* __restrict__ in,
                                                     bf16_t* __restrict__ out,
                                                     int R, int C) {
  __shared__ float tile[32][33];
  const int bz = blockIdx.z;
  const float* ip = in + (size_t)bz * R * C;
  bf16_t* op = out + (size_t)bz * R * C;
  const int r0 = blockIdx.y * 32, c0 = blockIdx.x * 32;
  const int tr = threadIdx.x >> 5, tc = threadIdx.x & 31;
#pragma unroll
  for (int i = 0; i < 4; ++i)
    tile[tr + i * 8][tc] = ip[(size_t)(r0 + tr + i * 8) * C + c0 + tc];
  __syncthreads();
#pragma unroll
  for (int i = 0; i < 4; ++i)
    op[(size_t)(c0 + tr + i * 8) * R + r0 + tc] = (bf16_t)tile[tc][tr + i * 8];
}

// ------------------------------------------------- V transpose bf16 -> bf16
// kvpre [B*S][4096] (V half starts at col 2048)  ->  vt [B][NKV][H][S]
__global__ __launch_bounds__(256) void vtrans_kernel(const bf16_t* __restrict__ vbase,
                                                     bf16_t* __restrict__ vt) {
  __shared__ bf16_t tile[32][33];
  const int bz = blockIdx.z;           // b*8+kv
  const int b = bz >> 3, kv = bz & 7;
  const int t0 = blockIdx.y * 32, h0 = blockIdx.x * 32;
  const int tr = threadIdx.x >> 5, tc = threadIdx.x & 31;
  const bf16_t* ip = vbase + (size_t)b * SS * KVP + kv * SH;
#pragma unroll
  for (int i = 0; i < 4; ++i)
    tile[tr + i * 8][tc] = ip[(size_t)(t0 + tr + i * 8) * KVP + h0 + tc];
  __syncthreads();
  bf16_t* op = vt + (size_t)bz * SH * SS;
#pragma unroll
  for (int i = 0; i < 4; ++i)
    op[(size_t)(h0 + tr + i * 8) * SS + t0 + tc] = tile[tc][tr + i * 8];
}

// --------------------------------------------------------- RoPE-K (vector)
__global__ __launch_bounds__(256) void rope_k_kernel(const bf16_t* __restrict__ kpre,
                                                     bf16_t* __restrict__ kb) {
  int idx = blockIdx.x * 256 + threadIdx.x;      // B*S*NKV*16
  const int i8 = (idx & 15) << 3;                // 0..120
  const int kv = (idx >> 4) & 7;
  const int row = idx >> 7;                      // 0..4095
  const int t = row & (SS - 1), b = row >> 11;
  const size_t ib = (size_t)row * KVP + kv * SH;
  bf16x8 x1 = *(const bf16x8*)(kpre + ib + i8);
  bf16x8 x2 = *(const bf16x8*)(kpre + ib + i8 + 128);
  bf16x8 r1, r2;
#pragma unroll
  for (int e = 0; e < 8; ++e) {
    float c_ = (float)(i8 + e);
    float inv = __expf(c_ * -0.07195578f);       // ln(10000)/128
    float fr = (float)t * inv;
    float cs = __cosf(fr), sn = __sinf(fr);
    float a = (float)x1[e], b2 = (float)x2[e];
    r1[e] = (bf16_t)(a * cs - b2 * sn);
    r2[e] = (bf16_t)(b2 * cs + a * sn);
  }
  const size_t ob = ((size_t)(b * SNKV + kv) * SS + t) * SH;
  *(bf16x8*)(kb + ob + i8) = r1;
  *(bf16x8*)(kb + ob + i8 + 128) = r2;
}

// ------------------------------------------------------------------- GEMM
// C[M][N] = A[M][K] * Bt[N][K]^T ; 256 x (NBW*64) tile, BK=32, 8 waves.
// 4-deep LDS ring, counted vmcnt (T4), setprio around MFMA (T5).
template <int NBW, bool OUT_BF16>
__global__ __launch_bounds__(512, 2) void gemm_bt(const bf16_t* __restrict__ A,
                                                  const bf16_t* __restrict__ Bt,
                                                  void* __restrict__ Cout,
                                                  int M, int N, int K) {
  constexpr int BN = NBW * 64;
  constexpr int MFR = (256 / (8 / NBW)) / 16;   // m-frags per wave (8 or 4)
  constexpr int ALOADS = 2;
  constexpr int BLOADS = NBW / 2;
  constexpr int LT = ALOADS + BLOADS;
  __shared__ bf16_t As[4][256 * 32];
  __shared__ bf16_t Bs[4][BN * 32];

  const int tid = threadIdx.x, lane = tid & 63, wid = tid >> 6;
  const int nbx = N / BN;
  const int nwg = (M >> 8) * nbx;
  const int cpx = nwg >> 3;
  const int lb = (blockIdx.x & 7) * cpx + (blockIdx.x >> 3);  // XCD chunking
  const int bx = lb % nbx, by = lb / nbx;
  const int row0 = by << 8;
  const int col0 = bx * BN;
  const int wr = wid / NBW, wc = wid % NBW;
  const int lr = lane & 15, hi = lane >> 4;

  const bf16_t* Arow = A + (size_t)row0 * K;
  const bf16_t* Brow = Bt + (size_t)col0 * K;

  auto stageA = [&](int t) {
    const int k0 = t << 5;
#pragma unroll
    for (int it = 0; it < ALOADS; ++it) {
      const int f = tid + (it << 9);
      async_ld16(Arow + (size_t)(f >> 2) * K + k0 + ((f & 3) << 3),
                 (char*)As[t & 3] + f * 16);
    }
  };
  auto stageB = [&](int t) {
    const int k0 = t << 5;
#pragma unroll
    for (int it = 0; it < BLOADS; ++it) {
      const int f = tid + (it << 9);
      async_ld16(Brow + (size_t)(f >> 2) * K + k0 + ((f & 3) << 3),
                 (char*)Bs[t & 3] + f * 16);
    }
  };

  f32x4 acc[MFR][4];
#pragma unroll
  for (int m = 0; m < MFR; ++m)
#pragma unroll
    for (int n = 0; n < 4; ++n) acc[m][n] = f32x4{0.f, 0.f, 0.f, 0.f};

  const int NT = K >> 5;
  stageA(0); stageB(0); stageA(1); stageB(1); stageA(2); stageB(2);
  asm volatile("s_waitcnt vmcnt(%0)" ::"i"(2 * LT) : "memory");
  __builtin_amdgcn_s_barrier();
  __builtin_amdgcn_sched_barrier(0);

  for (int t = 0; t < NT; ++t) {
    const bf16_t* Ab = &As[t & 3][(wr * (MFR * 16)) * 32];
    const bf16_t* Bb = &Bs[t & 3][(wc * 64) * 32];
    const bool pre = (t + 3 < NT);

    bf16x8 bfr[4];
#pragma unroll
    for (int nf = 0; nf < 4; ++nf)
      bfr[nf] = *(const bf16x8*)&Bb[(nf * 16 + lr) * 32 + hi * 8];

#pragma unroll
    for (int ph = 0; ph < MFR / 4; ++ph) {
      if (pre && ph == 0) stageA(t + 3);
      if (pre && ph == (MFR / 4) - 1) stageB(t + 3);
      bf16x8 af[4];
#pragma unroll
      for (int mf = 0; mf < 4; ++mf)
        af[mf] = *(const bf16x8*)&Ab[((ph * 4 + mf) * 16 + lr) * 32 + hi * 8];
      __builtin_amdgcn_s_setprio(1);
#pragma unroll
      for (int mf = 0; mf < 4; ++mf)
#pragma unroll
        for (int nf = 0; nf < 4; ++nf)
          acc[ph * 4 + mf][nf] = __builtin_amdgcn_mfma_f32_16x16x32_bf16(
              af[mf], bfr[nf], acc[ph * 4 + mf][nf], 0, 0, 0);
      __builtin_amdgcn_s_setprio(0);
    }

    if (t + 3 < NT) {
      asm volatile("s_waitcnt vmcnt(%0)" ::"i"(2 * LT) : "memory");
    } else if (t + 2 < NT) {
      asm volatile("s_waitcnt vmcnt(%0)" ::"i"(LT) : "memory");
    } else if (t + 1 < NT) {
      asm volatile("s_waitcnt vmcnt(0)" ::: "memory");
    }
    if (t + 1 < NT) {
      __builtin_amdgcn_s_barrier();
      __builtin_amdgcn_sched_barrier(0);
    }
  }

#pragma unroll
  for (int mf = 0; mf < MFR; ++mf) {
    const int r = row0 + wr * (MFR * 16) + mf * 16 + hi * 4;
#pragma unroll
    for (int nf = 0; nf < 4; ++nf) {
      const int c = col0 + wc * 64 + nf * 16 + lr;
#pragma unroll
      for (int j = 0; j < 4; ++j) {
        if (OUT_BF16)
          ((bf16_t*)Cout)[(size_t)(r + j) * N + c] = (bf16_t)acc[mf][nf][j];
        else
          ((float*)Cout)[(size_t)(r + j) * N + c] = acc[mf][nf][j];
      }
    }
  }
}

// -------------------------------------------------------------- attention
// Per block: (b, head, 128 q rows), 8 waves x 16 q rows each.
// KVB=64 double-buffer (R4 geometry: best measured). RoPE-Q fused into the
// Q register load. Fixed-base softmax (softcap bounds logits to +-50).
// LPT dispatch: heavy q-tiles (qt high) decode from LOW bid so dynamic
// block scheduling starts them first; XCD x owns kvh=x (4MB K/V = L2).
//   x=bid&7 -> kvh; y=bid>>3; qt=15-(y&15); head=(x<<1)|((y>>4)&1); b=y>>5.
// Swizzles (both-sides XOR involutions): K(512B pitch) chunk^=(row&7);
// V(128B pitch) chunk^=(row&7) with chunk<8 (PV ks<2).
#define QB 128
#define KVB 64
#define PP 72    // Ps pitch 144B

__global__ __launch_bounds__(512, 2) void attn_kernel(
    const bf16_t* __restrict__ Q,   // [B*S][NQ*H] (RAW projection output)
    const bf16_t* __restrict__ Kt,  // [B][NKV][S][H] (roped)
    const bf16_t* __restrict__ Vt,  // [B][NKV][H][S]
    bf16_t* __restrict__ AV) {      // [B*S][NQ*H]
  __shared__ bf16_t Ks[2][KVB * SH];   // 2 x 32 KB, row pitch 512B
  __shared__ bf16_t Vs[2][SH * KVB];   // 2 x 32 KB, row pitch 128B
  __shared__ bf16_t Ps[QB * PP];       // 18 KB

  const int tid = threadIdx.x, lane = tid & 63, wid = tid >> 6;
  // LPT + XCD-locality decode
  const int x = blockIdx.x & 7;
  const int y = blockIdx.x >> 3;       // 0..63
  const int qt = 15 - (y & 15);        // heavy tiles dispatch first
  const int head = (x << 1) | ((y >> 4) & 1);
  const int b = y >> 5;
  const int kvh = x;
  const int t0 = qt << 7;
  const int trw = t0 + wid * 16;       // this wave's first q row
  const int lr = lane & 15, hi = lane >> 4;
  const int lk = hi << 3;
  const int lq = hi;

  // Q load + fused RoPE + 1/16 scale (pair (c, c+128) = qf[ks], qf[ks+4])
  bf16x8 qf[8];
  {
    const bf16_t* qp = Q + ((size_t)(b * SS + trw + lr)) * (SNQ * SH) + head * SH + lk;
#pragma unroll
    for (int ks = 0; ks < 8; ++ks) qf[ks] = *(const bf16x8*)(qp + ks * 32);
    const float tpos = (float)(trw + lr);
#pragma unroll
    for (int ks = 0; ks < 4; ++ks) {
      bf16x8 a = qf[ks], b2 = qf[ks + 4];
      bf16x8 ra, rb;
#pragma unroll
      for (int e = 0; e < 8; ++e) {
        float c_ = (float)(ks * 32 + lk + e);
        float inv = __expf(c_ * -0.07195578f);
        float fr = tpos * inv;
        float cs = __cosf(fr), sn = __sinf(fr);
        float x1 = (float)a[e], x2 = (float)b2[e];
        ra[e] = (bf16_t)((x1 * cs - x2 * sn) * 0.0625f);
        rb[e] = (bf16_t)((x2 * cs + x1 * sn) * 0.0625f);
      }
      qf[ks] = ra; qf[ks + 4] = rb;
    }
  }

  f32x4 o[16];
#pragma unroll
  for (int i = 0; i < 16; ++i) o[i] = f32x4{0.f, 0.f, 0.f, 0.f};
  float lsum[4] = {0.f, 0.f, 0.f, 0.f};

  const bf16_t* Kb = Kt + (size_t)(b * SNKV + kvh) * SS * SH;
  const bf16_t* Vb = Vt + (size_t)(b * SNKV + kvh) * SH * SS;

  const int sv0 = (t0 >= SWIN) ? ((t0 >> 6) - 16) : 0;
  const int sv1 = (t0 >> 6) + 1;

  // DMA-stage K (64x256) + V^T (256x64) into buf d; both-sides XOR swizzle.
  auto stage = [&](int s0, int d) {
#pragma unroll
    for (int it = 0; it < 4; ++it) {
      const int f = tid + (it << 9);           // 0..2047
      {
        const int r = f >> 5, pc = f & 31;
        const int sc = pc ^ (r & 7);
        async_ld16(Kb + (size_t)(s0 + r) * SH + sc * 8, (char*)Ks[d] + f * 16);
      }
      {
        const int r = f >> 3, pc = f & 7;
        const int sc = pc ^ (r & 7);
        async_ld16(Vb + (size_t)r * SS + s0 + sc * 8, (char*)Vs[d] + f * 16);
      }
    }
  };

  stage(sv0 << 6, 0);
  __syncthreads();

  int cur = 0;
  for (int sv = sv0; sv <= sv1; ++sv, cur ^= 1) {
    if (sv < sv1) stage((sv + 1) << 6, cur ^ 1);

    const int s0 = sv << 6;
    const bool skip = (s0 > trw + 15) || (s0 + 63 < trw - (SWIN - 1));
    if (!skip) {
      const bf16_t* Kc = Ks[cur];
      const bf16_t* Vc = Vs[cur];
      // S = Q K^T (4 col-frags of 16)
      f32x4 sacc[4];
#pragma unroll
      for (int nt = 0; nt < 4; ++nt) sacc[nt] = f32x4{0.f, 0.f, 0.f, 0.f};
      __builtin_amdgcn_s_setprio(1);
#pragma unroll
      for (int ks = 0; ks < 8; ++ks) {
#pragma unroll
        for (int nt = 0; nt < 4; ++nt) {
          const int R = nt * 16 + lr;
          bf16x8 kf = *(const bf16x8*)((const char*)Kc + R * 512 +
                                       (((ks * 4 + hi) ^ (R & 7)) << 4));
          sacc[nt] = __builtin_amdgcn_mfma_f32_16x16x32_bf16(qf[ks], kf, sacc[nt], 0, 0, 0);
        }
      }
      __builtin_amdgcn_s_setprio(0);

      // softcap + exp (fixed base), write P
      const bool full = (s0 + 63 <= trw) && (s0 >= trw + 15 - (SWIN - 1));
      if (full) {
#pragma unroll
        for (int nt = 0; nt < 4; ++nt) {
#pragma unroll
          for (int j = 0; j < 4; ++j) {
            float u = sacc[nt][j] * 0.04f;
            float th = 50.f - 100.f * __builtin_amdgcn_rcpf(__expf(u) + 1.f);
            float p = __expf(th);
            lsum[j] += p;
            Ps[(wid * 16 + lq * 4 + j) * PP + nt * 16 + lr] = (bf16_t)p;
          }
        }
      } else {
#pragma unroll
        for (int nt = 0; nt < 4; ++nt) {
          const int s_ = s0 + nt * 16 + lr;
#pragma unroll
          for (int j = 0; j < 4; ++j) {
            const int t_ = trw + lq * 4 + j;
            float u = sacc[nt][j] * 0.04f;
            float th = 50.f - 100.f * __builtin_amdgcn_rcpf(__expf(u) + 1.f);
            const bool valid = (s_ <= t_) && (t_ - s_ < SWIN);
            float p = valid ? __expf(th) : 0.f;
            lsum[j] += p;
            Ps[(wid * 16 + lq * 4 + j) * PP + nt * 16 + lr] = (bf16_t)p;
          }
        }
      }

      // O += P V   (P rows wave-local: no barrier needed)
      __builtin_amdgcn_s_setprio(1);
#pragma unroll
      for (int ks = 0; ks < 2; ++ks) {
        bf16x8 pf = *(const bf16x8*)&Ps[(wid * 16 + lr) * PP + ks * 32 + lk];
#pragma unroll
        for (int nt = 0; nt < 16; ++nt) {
          const int R = nt * 16 + lr;
          bf16x8 vf = *(const bf16x8*)((const char*)Vc + R * 128 +
                                       (((ks * 4 + hi) ^ (R & 7)) << 4));
          o[nt] = __builtin_amdgcn_mfma_f32_16x16x32_bf16(pf, vf, o[nt], 0, 0, 0);
        }
      }
      __builtin_amdgcn_s_setprio(0);
    }

    __syncthreads();
  }

#pragma unroll
  for (int j = 0; j < 4; ++j) {
    float l = lsum[j];
    l += __shfl_xor(l, 1);
    l += __shfl_xor(l, 2);
    l += __shfl_xor(l, 4);
    l += __shfl_xor(l, 8);
    const float inv = 1.f / l;
    const int t_ = trw + lq * 4 + j;
    bf16_t* op = AV + ((size_t)(b * SS + t_)) * (SNQ * SH) + head * SH;
#pragma unroll
    for (int nt = 0; nt < 16; ++nt) op[nt * 16 + lr] = (bf16_t)(o[nt][j] * inv);
  }
}

// ------------------------------------------------------------------- host
extern "C" void kernel_launch(void* const* d_in, const int* in_sizes, int n_in,
                              void* d_out, int out_size, void* d_ws, size_t ws_size,
                              hipStream_t stream) {
  const float* x = (const float*)d_in[0];
  const float* Wq = (const float*)d_in[1];
  const float* Wk = (const float*)d_in[2];
  const float* Wv = (const float*)d_in[3];
  const float* Wo = (const float*)d_in[4];
  float* out = (float*)d_out;

  char* ws = (char*)d_ws;
  size_t off = 0;
  auto alloc = [&](size_t elems) {
    bf16_t* p = (bf16_t*)(ws + off);
    off += ((elems * 2 + 255) & ~(size_t)255);
    return p;
  };
  const size_t MS = (size_t)SB * SS;        // 4096 rows
  bf16_t* xb    = alloc(MS * SD);                 // [4096][2048]
  bf16_t* wqT   = alloc((size_t)SNQ * SH * SD);   // [4096][2048]
  bf16_t* wkvT  = alloc((size_t)2 * SNKV * SH * SD); // K rows then V rows
  bf16_t* woT   = alloc((size_t)SD * SNQ * SH);   // [2048][4096]
  bf16_t* qb    = alloc(MS * SNQ * SH);           // [4096][4096]
  bf16_t* kvpre = alloc(MS * 2 * SNKV * SH);      // [4096][4096] K | V cols
  bf16_t* kb    = alloc(MS * SNKV * SH);          // [B][NKV][S][H]
  bf16_t* vt    = alloc(MS * SNKV * SH);          // [B][NKV][H][S]
  bf16_t* av    = alloc(MS * SNQ * SH);           // [4096][4096]
  (void)ws_size;  // ~218 MB

  cvt_kernel<<<(MS * SD / 4) / 256, 256, 0, stream>>>(x, xb);
  wtrans_kernel<<<dim3(8, 64, 16), 256, 0, stream>>>(Wq, wqT, SD, SH);
  wtrans_kernel<<<dim3(8, 64, 8), 256, 0, stream>>>(Wk, wkvT, SD, SH);
  wtrans_kernel<<<dim3(8, 64, 8), 256, 0, stream>>>(Wv, wkvT + (size_t)SNKV * SH * SD, SD, SH);
  wtrans_kernel<<<dim3(64, 128, 1), 256, 0, stream>>>(Wo, woT, SNQ * SH, SD);

  gemm_bt<4, true><<<256, 512, 0, stream>>>(xb, wqT, qb, 4096, 4096, 2048);
  gemm_bt<4, true><<<256, 512, 0, stream>>>(xb, wkvT, kvpre, 4096, 4096, 2048);

  rope_k_kernel<<<(MS * SNKV * 16) / 256, 256, 0, stream>>>(kvpre, kb);
  vtrans_kernel<<<dim3(8, 64, 16), 256, 0, stream>>>(kvpre + 2048, vt);

  attn_kernel<<<512, 512, 0, stream>>>(qb, kb, vt, av);

  gemm_bt<2, false><<<256, 512, 0, stream>>>(av, woT, out, 4096, 2048, 4096);
}